// Round 4
// baseline (843.750 us; speedup 1.0000x reference)
//
#include <hip/hip_runtime.h>

#define NN 50000
#define NE 800000
#define EPS 1e-5f

typedef __attribute__((ext_vector_type(8))) short s16x8;
typedef __attribute__((ext_vector_type(4))) short s16x4;
typedef __attribute__((ext_vector_type(4))) float f32x4;

// ---------------------------------------------------------------------------
// ws layout (EXACTLY the round-1-proven 307,204,096 bytes):
//   0        : st, 1024 floats (4 KB)
//   4096     : xbuf bf16 [E][64] (102,400,000 B); after k_y_stats this region
//              is dead and startF (int[NN+1]) overlays it.
//   102404096: ybuf bf16 [E][128] (204,800,000 B), rows permuted by slot[]
// st float offsets:
//   0 S_e[64], 64 Q_e[64], 128 S_y[128], 256 Q_y[128], 384 S_n[64], 448 Q_n[64]
//   512 A_e[64], 576 C_e[64], 640 A_y[128], 768 C_y[128], 896 A_n[64], 960 C_n[64]
// d_out (12.8 MB) doubles as scratch until k_gather writes agg:
//   BT @0 (49152), BTe @49152 (8192), biasY @57344 (512), cnt @57856 (200000),
//   cur @257856 (200000), slot @457856 (3200000), start_tmp @3657856 (200004),
//   nfb @3857920 (6400000)  -- all dead before k_gather runs.
// ---------------------------------------------------------------------------

__device__ __forceinline__ short f2bf(float f) {
    unsigned u = __builtin_bit_cast(unsigned, f);
    unsigned r = (u + 0x7FFFu + ((u >> 16) & 1u)) >> 16;
    return (short)r;
}
__device__ __forceinline__ float bf2f(short s) {
    unsigned u = ((unsigned)(unsigned short)s) << 16;
    return __builtin_bit_cast(float, u);
}
__device__ __forceinline__ float silu_f(float x) { return x / (1.0f + __expf(-x)); }
__device__ __forceinline__ float softplus_f(float x) {
    return fmaxf(x, 0.0f) + log1pf(__expf(-fabsf(x)));
}
// XOR swizzle for row-major [128][192]-short LDS tile (16 B-slot granularity).
__device__ __forceinline__ int swz(int row, int col) {
    return row * 192 + (col ^ ((row & 7) << 3));
}

// ------------- prep: transpose weights to bf16, combined bias ---------------
__global__ void k_prep(const float* __restrict__ Wm, const float* __restrict__ Ws,
                       const float* __restrict__ We, const float* __restrict__ bm,
                       const float* __restrict__ bs, short* __restrict__ BT,
                       short* __restrict__ BTe, float* __restrict__ biasY)
{
    int i = blockIdx.x * 256 + threadIdx.x;
    if (i < 24576) {
        int n = i / 192, k = i % 192;
        float w = (n < 64) ? Wm[k * 64 + n] : Ws[k * 64 + (n - 64)];
        BT[n * 192 + k] = f2bf(w);
    } else if (i < 28672) {
        int j = i - 24576;
        int n = j >> 6, k = j & 63;
        BTe[n * 64 + k] = f2bf(We[k * 64 + n]);
    } else if (i < 28800) {
        int j = i - 28672;
        biasY[j] = (j < 64) ? bm[j] : bs[j - 64];
    }
}

// ------------- node feats -> bf16 -------------------------------------------
__global__ void k_nfb(const float* __restrict__ nf, short* __restrict__ nfb)
{
    long i = (long)blockIdx.x * 256 + threadIdx.x;      // s16x8 index
    if (i >= (long)NN * 64 / 8) return;
    float4 a = ((const float4*)nf)[i * 2];
    float4 b = ((const float4*)nf)[i * 2 + 1];
    s16x8 o;
    o[0] = f2bf(a.x); o[1] = f2bf(a.y); o[2] = f2bf(a.z); o[3] = f2bf(a.w);
    o[4] = f2bf(b.x); o[5] = f2bf(b.y); o[6] = f2bf(b.z); o[7] = f2bf(b.w);
    ((s16x8*)nfb)[i] = o;
}

// ------------- CSR build -----------------------------------------------------
__global__ void k_hist(const int* __restrict__ dst, int* __restrict__ cnt)
{
    int e = blockIdx.x * 256 + threadIdx.x;
    if (e < NE) atomicAdd(&cnt[dst[e]], 1);
}

__global__ void k_scan(const int* __restrict__ cnt, int* __restrict__ start_tmp,
                       int* __restrict__ cur)
{
    __shared__ int ps[256];
    const int t = threadIdx.x;
    const int CH = 196;                                  // 256*196 = 50176 >= NN
    int base = t * CH;
    int sum = 0;
    for (int i = 0; i < CH; ++i) {
        int idx = base + i;
        if (idx < NN) sum += cnt[idx];
    }
    ps[t] = sum;
    __syncthreads();
    for (int off = 1; off < 256; off <<= 1) {            // inclusive scan
        int v = (t >= off) ? ps[t - off] : 0;
        __syncthreads();
        ps[t] += v;
        __syncthreads();
    }
    int run = (t == 0) ? 0 : ps[t - 1];                  // exclusive prefix
    for (int i = 0; i < CH; ++i) {
        int idx = base + i;
        if (idx < NN) {
            start_tmp[idx] = run;
            cur[idx] = run;
            run += cnt[idx];
        }
    }
    if (t == 255) start_tmp[NN] = run;                   // == NE
}

__global__ void k_slot(const int* __restrict__ dst, int* __restrict__ cur,
                       int* __restrict__ slot)
{
    int e = blockIdx.x * 256 + threadIdx.x;
    if (e < NE) slot[e] = atomicAdd(&cur[dst[e]], 1);
}

__global__ void k_copy(const int* __restrict__ a, int* __restrict__ b)
{
    int i = blockIdx.x * 256 + threadIdx.x;
    if (i <= NN) b[i] = a[i];
}

// ------------- BN finalize: A = g*rsqrt(var+eps), C = beta - mean*A ----------
__global__ void k_fin(const float* __restrict__ S, const float* __restrict__ Q,
                      const float* __restrict__ g, const float* __restrict__ b,
                      float inv_cnt, float* __restrict__ A, float* __restrict__ C)
{
    int j = threadIdx.x;
    float m = S[j] * inv_cnt;
    float v = Q[j] * inv_cnt - m * m;
    float a = g[j] * rsqrtf(v + EPS);
    A[j] = a;
    C[j] = b[j] - m * a;
}

// ------------- Phase 1: x = ef @ W_e + b_e (MFMA bf16); stats; store xbuf ----
__global__ __launch_bounds__(256, 4) void k_xe_m(
    const float* __restrict__ ef, const short* __restrict__ BTe,
    const float* __restrict__ be_, float* __restrict__ st,
    short* __restrict__ xbuf)
{
    __shared__ short sA[128][72];
    __shared__ short sB[64][72];
    __shared__ float sSQ[128];
    __shared__ float sBe[64];
    const int tx = threadIdx.x;
    const long e0 = (long)blockIdx.x * 128;

    if (tx < 128) sSQ[tx] = 0.f;
    if (tx < 64) sBe[tx] = be_[tx];
    #pragma unroll
    for (int i = tx; i < 512; i += 256) {
        int n = i >> 3, c = (i & 7) * 8;
        *(s16x8*)&sB[n][c] = ((const s16x8*)BTe)[i];
    }
    {
        const int e = tx >> 1, half = tx & 1;
        const float* p = ef + (e0 + e) * 64 + 32 * half;
        #pragma unroll
        for (int c = 0; c < 32; c += 4) {
            float4 v = *(const float4*)(p + c);
            s16x4 w; w.x = f2bf(v.x); w.y = f2bf(v.y); w.z = f2bf(v.z); w.w = f2bf(v.w);
            *(s16x4*)&sA[e][32 * half + c] = w;
        }
    }
    __syncthreads();

    const int w = tx >> 6, lane = tx & 63, lr = lane & 15, lg = lane >> 4;
    f32x4 acc[2][4];
    for (int m = 0; m < 2; ++m) for (int n = 0; n < 4; ++n)
        for (int q = 0; q < 4; ++q) acc[m][n][q] = 0.f;

    #pragma unroll
    for (int ks = 0; ks < 2; ++ks) {
        s16x8 a[2], b[4];
        #pragma unroll
        for (int m = 0; m < 2; ++m) a[m] = *(const s16x8*)&sA[32 * w + 16 * m + lr][ks * 32 + 8 * lg];
        #pragma unroll
        for (int n = 0; n < 4; ++n) b[n] = *(const s16x8*)&sB[16 * n + lr][ks * 32 + 8 * lg];
        #pragma unroll
        for (int m = 0; m < 2; ++m)
            #pragma unroll
            for (int n = 0; n < 4; ++n)
                acc[m][n] = __builtin_amdgcn_mfma_f32_16x16x32_bf16(a[m], b[n], acc[m][n], 0, 0, 0);
    }

    #pragma unroll
    for (int n = 0; n < 4; ++n) {
        int col = 16 * n + lr;
        float b = sBe[col];
        float s = 0.f, q = 0.f;
        #pragma unroll
        for (int m = 0; m < 2; ++m)
            #pragma unroll
            for (int r = 0; r < 4; ++r) { float y = acc[m][n][r] + b; s += y; q += y * y; }
        s += __shfl_xor(s, 16); s += __shfl_xor(s, 32);
        q += __shfl_xor(q, 16); q += __shfl_xor(q, 32);
        if (lg == 0) { atomicAdd(&sSQ[col], s); atomicAdd(&sSQ[64 + col], q); }
    }
    __syncthreads();
    short* sX = &sA[0][0];                                // overlay [128][64]
    #pragma unroll
    for (int n = 0; n < 4; ++n) {
        int col = 16 * n + lr;
        float b = sBe[col];
        #pragma unroll
        for (int m = 0; m < 2; ++m)
            #pragma unroll
            for (int r = 0; r < 4; ++r) {
                int row = 32 * w + 16 * m + 4 * lg + r;
                sX[row * 64 + col] = f2bf(acc[m][n][r] + b);
            }
    }
    __syncthreads();
    #pragma unroll
    for (int i = tx; i < 1024; i += 256)
        ((s16x8*)(xbuf + e0 * 64))[i] = ((const s16x8*)sX)[i];
    if (tx < 64) atomicAdd(&st[tx], sSQ[tx]);
    else if (tx < 128) atomicAdd(&st[64 + (tx - 64)], sSQ[tx]);
}

// ------------- Phase 1.5: hm = silu(bn_e(x)) in place on xbuf ----------------
__global__ __launch_bounds__(256) void k_hm(short* __restrict__ xbuf,
                                            const float* __restrict__ st)
{
    __shared__ float sAC[128];
    if (threadIdx.x < 128) sAC[threadIdx.x] = st[512 + threadIdx.x];
    __syncthreads();
    const long total = (long)NE * 64 / 8;
    for (long t = (long)blockIdx.x * 256 + threadIdx.x; t < total;
         t += (long)gridDim.x * 256) {
        s16x8 v = ((s16x8*)xbuf)[t];
        int j0 = (int)((t * 8) & 63);
        s16x8 o;
        #pragma unroll
        for (int k = 0; k < 8; ++k) {
            int j = j0 + k;
            float x = bf2f(v[k]);
            o[k] = f2bf(silu_f(fmaf(x, sAC[j], sAC[64 + j])));
        }
        ((s16x8*)xbuf)[t] = o;
    }
}

// ------------- Phase 2: y = h_combine @ [W_m|W_s] + bias; stats; store -------
// Single big GEMM pass. Stages are pure bf16 copies (nfb + precomputed hm).
// Stores y rows permuted to dst-sorted position slot[e] for atomic-free gather.
__global__ __launch_bounds__(256, 3) void k_y_stats(
    const short* __restrict__ nfb, const int* __restrict__ src,
    const int* __restrict__ dst, const short* __restrict__ hmb,
    const short* __restrict__ BT, const float* __restrict__ biasY,
    const int* __restrict__ slot, float* __restrict__ st,
    short* __restrict__ ybuf)
{
    __shared__ s16x8 sAv[128 * 24];                      // [128][192] shorts
    short* sA = (short*)sAv;
    __shared__ float sSQ[256];
    __shared__ float sBias[128];
    __shared__ int   sSlot[128];

    const int tx = threadIdx.x;
    const long e0 = (long)blockIdx.x * 128;

    sSQ[tx] = 0.f;
    if (tx < 128) { sBias[tx] = biasY[tx]; sSlot[tx] = slot[e0 + tx]; }

    {                                                    // stage A: pure copies
        const int e = tx >> 1, half = tx & 1;
        int sn = src[e0 + e], dn = dst[e0 + e];
        const short* ps = nfb + (size_t)sn * 64 + 32 * half;
        const short* pd = nfb + (size_t)dn * 64 + 32 * half;
        const short* ph = hmb + (size_t)(e0 + e) * 64 + 32 * half;
        #pragma unroll
        for (int c = 0; c < 32; c += 8) {
            *(s16x8*)&sA[swz(e, 32 * half + c)]        = *(const s16x8*)(ps + c);
            *(s16x8*)&sA[swz(e, 64 + 32 * half + c)]   = *(const s16x8*)(pd + c);
            *(s16x8*)&sA[swz(e, 128 + 32 * half + c)]  = *(const s16x8*)(ph + c);
        }
    }
    __syncthreads();

    const int w = tx >> 6, lane = tx & 63, lr = lane & 15, lg = lane >> 4;
    const int wr = w >> 1, wc = w & 1;
    f32x4 acc[4][4];
    for (int m = 0; m < 4; ++m) for (int n = 0; n < 4; ++n)
        for (int q = 0; q < 4; ++q) acc[m][n][q] = 0.f;

    const s16x8* Bg = (const s16x8*)BT;                  // [128 rows][24 frags]
    const int brow = (64 * wc + lr) * 24 + lg;

    #pragma unroll
    for (int ks = 0; ks < 6; ++ks) {
        s16x8 a[4], b[4];
        #pragma unroll
        for (int m = 0; m < 4; ++m)
            a[m] = *(const s16x8*)&sA[swz(64 * wr + 16 * m + lr, ks * 32 + 8 * lg)];
        #pragma unroll
        for (int n = 0; n < 4; ++n)
            b[n] = Bg[brow + 384 * n + 4 * ks];
        #pragma unroll
        for (int m = 0; m < 4; ++m)
            #pragma unroll
            for (int n = 0; n < 4; ++n)
                acc[m][n] = __builtin_amdgcn_mfma_f32_16x16x32_bf16(a[m], b[n], acc[m][n], 0, 0, 0);
    }

    __syncthreads();                                     // all sA frag reads done
    // bias + stats + write y rows (bf16) into sA overlay (swizzled)
    #pragma unroll
    for (int n = 0; n < 4; ++n) {
        int col = 64 * wc + 16 * n + lr;
        float b = sBias[col];
        float s = 0.f, q = 0.f;
        #pragma unroll
        for (int m = 0; m < 4; ++m)
            #pragma unroll
            for (int r = 0; r < 4; ++r) {
                float y = acc[m][n][r] + b;
                s += y; q += y * y;
                int row = 64 * wr + 16 * m + 4 * lg + r;
                sA[row * 192 + (col ^ ((row & 7) << 3))] = f2bf(y);
            }
        s += __shfl_xor(s, 16); s += __shfl_xor(s, 32);
        q += __shfl_xor(q, 16); q += __shfl_xor(q, 32);
        if (lg == 0) { atomicAdd(&sSQ[col], s); atomicAdd(&sSQ[128 + col], q); }
    }
    __syncthreads();
    // cooperative permuted store: 128 rows x 16 frags of 16 B
    #pragma unroll
    for (int i = tx; i < 2048; i += 256) {
        int row = i >> 4, frag = i & 15;
        s16x8 v = *(const s16x8*)&sA[swz(row, frag * 8)];
        *(s16x8*)(ybuf + (size_t)sSlot[row] * 128 + frag * 8) = v;
    }
    if (tx < 128) atomicAdd(&st[128 + tx], sSQ[tx]);
    else atomicAdd(&st[256 + (tx - 128)], sSQ[tx]);
}

// ------------- Phase 3: atomic-free gather: one wave per node ----------------
__global__ __launch_bounds__(256) void k_gather(
    const short* __restrict__ ybuf, const int* __restrict__ startF,
    const float* __restrict__ st, float* __restrict__ agg)
{
    __shared__ float sA_[128], sC_[128];
    const int tx = threadIdx.x;
    if (tx < 128) { sA_[tx] = st[640 + tx]; sC_[tx] = st[768 + tx]; }
    __syncthreads();
    const int w = tx >> 6, j = tx & 63;
    const int n = blockIdx.x * 4 + w;
    const int s = startF[n], e = startF[n + 1];
    const float am = sA_[j], cm = sC_[j], as = sA_[64 + j], cs = sC_[64 + j];
    float acc = 0.f;
    for (int i = s; i < e; ++i) {
        const short* row = ybuf + (size_t)i * 128;
        float ym = bf2f(row[j]);
        float ys = bf2f(row[64 + j]);
        acc += silu_f(fmaf(ym, am, cm)) * softplus_f(fmaf(ys, as, cs));
    }
    agg[(size_t)n * 64 + j] = acc;
}

// ------------- Phase 4: agg column stats -------------------------------------
__global__ __launch_bounds__(256) void k_aggstats(const float* __restrict__ agg,
                                                  float* __restrict__ st)
{
    __shared__ float red[2][4][64];
    float ls = 0.f, lq = 0.f;
    const long total = (long)NN * 64;
    for (long t = (long)blockIdx.x * 256 + threadIdx.x; t < total;
         t += (long)gridDim.x * 256) {
        float a = agg[t];
        ls += a; lq += a * a;
    }
    int j = threadIdx.x & 63, g = threadIdx.x >> 6;
    red[0][g][j] = ls; red[1][g][j] = lq;
    __syncthreads();
    if (threadIdx.x < 64) {
        float s = red[0][0][j] + red[0][1][j] + red[0][2][j] + red[0][3][j];
        atomicAdd(&st[384 + j], s);
    } else if (threadIdx.x < 128) {
        int jj = threadIdx.x - 64;
        float q = red[1][0][jj] + red[1][1][jj] + red[1][2][jj] + red[1][3][jj];
        atomicAdd(&st[448 + jj], q);
    }
}

// ------------- Phase 5: out = softplus(bn_n(agg) + nf), in place -------------
__global__ __launch_bounds__(256) void k_out(float* __restrict__ outagg,
                                             const float* __restrict__ nf,
                                             const float* __restrict__ st)
{
    long t = (long)blockIdx.x * 256 + threadIdx.x;
    int j = (int)(t & 63);
    float a = outagg[t];
    outagg[t] = softplus_f(fmaf(a, st[896 + j], st[960 + j]) + nf[t]);
}

extern "C" void kernel_launch(void* const* d_in, const int* in_sizes, int n_in,
                              void* d_out, int out_size, void* d_ws, size_t ws_size,
                              hipStream_t stream)
{
    (void)in_sizes; (void)n_in; (void)out_size; (void)ws_size;
    const float* nf  = (const float*)d_in[0];
    const float* ef  = (const float*)d_in[1];
    const int*   src = (const int*)d_in[2];
    const int*   dst = (const int*)d_in[3];
    const float* We  = (const float*)d_in[4];
    const float* be_ = (const float*)d_in[5];
    const float* ge  = (const float*)d_in[6];
    const float* bee = (const float*)d_in[7];
    const float* Wm  = (const float*)d_in[8];
    const float* bm  = (const float*)d_in[9];
    const float* gm  = (const float*)d_in[10];
    const float* bem = (const float*)d_in[11];
    const float* Ws  = (const float*)d_in[12];
    const float* bs  = (const float*)d_in[13];
    const float* gs  = (const float*)d_in[14];
    const float* bes = (const float*)d_in[15];
    const float* gn  = (const float*)d_in[16];
    const float* ben = (const float*)d_in[17];

    // ws (proven-size layout)
    float* st    = (float*)d_ws;
    short* xbuf  = (short*)((char*)d_ws + 4096);
    int*   startF= (int*)((char*)d_ws + 4096);            // overlays dead xbuf
    short* ybuf  = (short*)((char*)d_ws + 4096 + 102400000);

    // d_out scratch (dead before k_gather)
    char* ob = (char*)d_out;
    short* BT        = (short*)ob;
    short* BTe       = (short*)(ob + 49152);
    float* biasY     = (float*)(ob + 57344);
    int*   cnt       = (int*)(ob + 57856);
    int*   cur       = (int*)(ob + 257856);
    int*   slot      = (int*)(ob + 457856);
    int*   start_tmp = (int*)(ob + 3657856);
    short* nfb       = (short*)(ob + 3857920);
    float* agg       = (float*)d_out;

    hipMemsetAsync(st, 0, 4096, stream);
    hipMemsetAsync(cnt, 0, 200000, stream);

    k_prep<<<113, 256, 0, stream>>>(Wm, Ws, We, bm, bs, BT, BTe, biasY);
    k_nfb<<<1563, 256, 0, stream>>>(nf, nfb);
    k_hist<<<3125, 256, 0, stream>>>(dst, cnt);
    k_scan<<<1, 256, 0, stream>>>(cnt, start_tmp, cur);
    k_slot<<<3125, 256, 0, stream>>>(dst, cur, slot);

    k_xe_m<<<NE / 128, 256, 0, stream>>>(ef, BTe, be_, st, xbuf);
    k_fin<<<1, 64, 0, stream>>>(st + 0, st + 64, ge, bee, 1.0f / NE, st + 512, st + 576);
    k_hm<<<4096, 256, 0, stream>>>(xbuf, st);

    k_y_stats<<<NE / 128, 256, 0, stream>>>(nfb, src, dst, xbuf, BT, biasY, slot, st, ybuf);
    k_fin<<<1, 64, 0, stream>>>(st + 128, st + 256, gm, bem, 1.0f / NE, st + 640, st + 768);
    k_fin<<<1, 64, 0, stream>>>(st + 192, st + 320, gs, bes, 1.0f / NE, st + 704, st + 832);

    k_copy<<<196, 256, 0, stream>>>(start_tmp, startF);   // xbuf now dead
    k_gather<<<NN / 4, 256, 0, stream>>>(ybuf, startF, st, agg);

    k_aggstats<<<1024, 256, 0, stream>>>(agg, st);
    k_fin<<<1, 64, 0, stream>>>(st + 384, st + 448, gn, ben, 1.0f / NN, st + 896, st + 960);

    k_out<<<NN * 64 / 256, 256, 0, stream>>>(agg, nf, st);
}

// Round 5
// 605.298 us; speedup vs baseline: 1.3939x; 1.3939x over previous
//
#include <hip/hip_runtime.h>

#define NN 50000
#define NE 800000
#define EPS 1e-5f

typedef __attribute__((ext_vector_type(8))) short s16x8;
typedef __attribute__((ext_vector_type(4))) short s16x4;
typedef __attribute__((ext_vector_type(4))) float f32x4;

// ---------------------------------------------------------------------------
// ws layout (round-1-proven >= 307,204,096 bytes):
//   0        : st, 1024 floats (4 KB)
//   4096     : xbuf bf16 [E][64] (102,400,000 B); holds RAW x = ef@We+be.
//              After k_y_stats this region is dead; startF (int[NN+1])
//              overlays it for k_gather.
//   102404096: ybuf bf16 [E][128], rows permuted to dst-sorted slot order.
// st float offsets:
//   0 S_e[64], 64 Q_e[64], 128 S_y[128], 256 Q_y[128], 384 S_n[64], 448 Q_n[64]
//   512 A_e[64], 576 C_e[64], 640 A_y[128], 768 C_y[128], 896 A_n[64], 960 C_n[64]
// d_out (12.8 MB) doubles as scratch until k_gather writes agg:
//   BT @0 (49152), BTe @49152 (8192), biasY @57344 (512), cnt @57856 (200000),
//   cur @257856 (200000), slot @457856 (3200000), start_tmp @3657856 (200004),
//   nfb @3857920 (6400000)  -- all dead before k_gather runs.
// ---------------------------------------------------------------------------

__device__ __forceinline__ short f2bf(float f) {
    unsigned u = __builtin_bit_cast(unsigned, f);
    unsigned r = (u + 0x7FFFu + ((u >> 16) & 1u)) >> 16;
    return (short)r;
}
__device__ __forceinline__ float bf2f(short s) {
    unsigned u = ((unsigned)(unsigned short)s) << 16;
    return __builtin_bit_cast(float, u);
}
// cheap transcendentals: v_exp/v_log/v_rcp based (tolerance is ~2%)
__device__ __forceinline__ float silu_f(float x) {
    return x * __builtin_amdgcn_rcpf(1.0f + __expf(-x));
}
__device__ __forceinline__ float softplus_f(float x) {
    float t = __expf(-fabsf(x));
    return fmaxf(x, 0.0f) + __logf(1.0f + t);
}
// XOR swizzle for row-major [128][192]-short LDS tile (16 B-slot granularity).
__device__ __forceinline__ int swz(int row, int col) {
    return row * 192 + (col ^ ((row & 7) << 3));
}

// ------------- prep: transpose weights to bf16, combined bias ---------------
__global__ void k_prep(const float* __restrict__ Wm, const float* __restrict__ Ws,
                       const float* __restrict__ We, const float* __restrict__ bm,
                       const float* __restrict__ bs, short* __restrict__ BT,
                       short* __restrict__ BTe, float* __restrict__ biasY)
{
    int i = blockIdx.x * 256 + threadIdx.x;
    if (i < 24576) {
        int n = i / 192, k = i % 192;
        float w = (n < 64) ? Wm[k * 64 + n] : Ws[k * 64 + (n - 64)];
        BT[n * 192 + k] = f2bf(w);
    } else if (i < 28672) {
        int j = i - 24576;
        int n = j >> 6, k = j & 63;
        BTe[n * 64 + k] = f2bf(We[k * 64 + n]);
    } else if (i < 28800) {
        int j = i - 28672;
        biasY[j] = (j < 64) ? bm[j] : bs[j - 64];
    }
}

// ------------- node feats -> bf16 -------------------------------------------
__global__ void k_nfb(const float* __restrict__ nf, short* __restrict__ nfb)
{
    long i = (long)blockIdx.x * 256 + threadIdx.x;      // s16x8 index
    if (i >= (long)NN * 64 / 8) return;
    float4 a = ((const float4*)nf)[i * 2];
    float4 b = ((const float4*)nf)[i * 2 + 1];
    s16x8 o;
    o[0] = f2bf(a.x); o[1] = f2bf(a.y); o[2] = f2bf(a.z); o[3] = f2bf(a.w);
    o[4] = f2bf(b.x); o[5] = f2bf(b.y); o[6] = f2bf(b.z); o[7] = f2bf(b.w);
    ((s16x8*)nfb)[i] = o;
}

// ------------- CSR build -----------------------------------------------------
__global__ void k_hist(const int* __restrict__ dst, int* __restrict__ cnt)
{
    int e = blockIdx.x * 256 + threadIdx.x;
    if (e < NE) atomicAdd(&cnt[dst[e]], 1);
}

__global__ void k_scan(const int* __restrict__ cnt, int* __restrict__ start_tmp,
                       int* __restrict__ cur)
{
    __shared__ int ps[256];
    const int t = threadIdx.x;
    const int CH = 196;                                  // 256*196 = 50176 >= NN
    int base = t * CH;
    int sum = 0;
    for (int i = 0; i < CH; i += 4) {
        int idx = base + i;
        if (idx < NN) { int4 v = *(const int4*)&cnt[idx]; sum += v.x + v.y + v.z + v.w; }
    }
    ps[t] = sum;
    __syncthreads();
    for (int off = 1; off < 256; off <<= 1) {            // inclusive scan
        int v = (t >= off) ? ps[t - off] : 0;
        __syncthreads();
        ps[t] += v;
        __syncthreads();
    }
    int run = (t == 0) ? 0 : ps[t - 1];                  // exclusive prefix
    for (int i = 0; i < CH; i += 4) {
        int idx = base + i;
        if (idx < NN) {
            int4 v = *(const int4*)&cnt[idx];
            int4 o; o.x = run; o.y = run + v.x; o.z = o.y + v.y; o.w = o.z + v.z;
            *(int4*)&start_tmp[idx] = o;
            *(int4*)&cur[idx] = o;
            run = o.w + v.w;
        }
    }
    if (t == 255) start_tmp[NN] = run;                   // == NE
}

__global__ void k_slot(const int* __restrict__ dst, int* __restrict__ cur,
                       int* __restrict__ slot)
{
    int e = blockIdx.x * 256 + threadIdx.x;
    if (e < NE) slot[e] = atomicAdd(&cur[dst[e]], 1);
}

__global__ void k_copy(const int* __restrict__ a, int* __restrict__ b)
{
    int i = blockIdx.x * 256 + threadIdx.x;
    if (i <= NN) b[i] = a[i];
}

// ------------- BN finalize: A = g*rsqrt(var+eps), C = beta - mean*A ----------
__global__ void k_fin(const float* __restrict__ S, const float* __restrict__ Q,
                      const float* __restrict__ g, const float* __restrict__ b,
                      float inv_cnt, float* __restrict__ A, float* __restrict__ C)
{
    int j = threadIdx.x;
    float m = S[j] * inv_cnt;
    float v = Q[j] * inv_cnt - m * m;
    float a = g[j] * rsqrtf(v + EPS);
    A[j] = a;
    C[j] = b[j] - m * a;
}

// merged finalize for both y-BNs (j 0..127: m-half then s-half)
__global__ void k_finY(const float* __restrict__ st_,
                       const float* __restrict__ gm, const float* __restrict__ bem,
                       const float* __restrict__ gs, const float* __restrict__ bes,
                       float* __restrict__ A, float* __restrict__ C)
{
    int j = threadIdx.x;
    float g = (j < 64) ? gm[j] : gs[j - 64];
    float b = (j < 64) ? bem[j] : bes[j - 64];
    float m = st_[128 + j] * (1.0f / NE);
    float v = st_[256 + j] * (1.0f / NE) - m * m;
    float a = g * rsqrtf(v + EPS);
    A[j] = a;
    C[j] = b - m * a;
}

// ------------- Phase 1: x = ef @ W_e + b_e (MFMA bf16); stats; store xbuf ----
__global__ __launch_bounds__(256, 4) void k_xe_m(
    const float* __restrict__ ef, const short* __restrict__ BTe,
    const float* __restrict__ be_, float* __restrict__ st,
    short* __restrict__ xbuf)
{
    __shared__ short sA[128][72];
    __shared__ short sB[64][72];
    __shared__ float sSQ[128];
    __shared__ float sBe[64];
    const int tx = threadIdx.x;
    const long e0 = (long)blockIdx.x * 128;

    if (tx < 128) sSQ[tx] = 0.f;
    if (tx < 64) sBe[tx] = be_[tx];
    #pragma unroll
    for (int i = tx; i < 512; i += 256) {
        int n = i >> 3, c = (i & 7) * 8;
        *(s16x8*)&sB[n][c] = ((const s16x8*)BTe)[i];
    }
    {
        const int e = tx >> 1, half = tx & 1;
        const float* p = ef + (e0 + e) * 64 + 32 * half;
        #pragma unroll
        for (int c = 0; c < 32; c += 4) {
            float4 v = *(const float4*)(p + c);
            s16x4 w; w.x = f2bf(v.x); w.y = f2bf(v.y); w.z = f2bf(v.z); w.w = f2bf(v.w);
            *(s16x4*)&sA[e][32 * half + c] = w;
        }
    }
    __syncthreads();

    const int w = tx >> 6, lane = tx & 63, lr = lane & 15, lg = lane >> 4;
    f32x4 acc[2][4];
    for (int m = 0; m < 2; ++m) for (int n = 0; n < 4; ++n)
        for (int q = 0; q < 4; ++q) acc[m][n][q] = 0.f;

    #pragma unroll
    for (int ks = 0; ks < 2; ++ks) {
        s16x8 a[2], b[4];
        #pragma unroll
        for (int m = 0; m < 2; ++m) a[m] = *(const s16x8*)&sA[32 * w + 16 * m + lr][ks * 32 + 8 * lg];
        #pragma unroll
        for (int n = 0; n < 4; ++n) b[n] = *(const s16x8*)&sB[16 * n + lr][ks * 32 + 8 * lg];
        #pragma unroll
        for (int m = 0; m < 2; ++m)
            #pragma unroll
            for (int n = 0; n < 4; ++n)
                acc[m][n] = __builtin_amdgcn_mfma_f32_16x16x32_bf16(a[m], b[n], acc[m][n], 0, 0, 0);
    }

    #pragma unroll
    for (int n = 0; n < 4; ++n) {
        int col = 16 * n + lr;
        float b = sBe[col];
        float s = 0.f, q = 0.f;
        #pragma unroll
        for (int m = 0; m < 2; ++m)
            #pragma unroll
            for (int r = 0; r < 4; ++r) { float y = acc[m][n][r] + b; s += y; q += y * y; }
        s += __shfl_xor(s, 16); s += __shfl_xor(s, 32);
        q += __shfl_xor(q, 16); q += __shfl_xor(q, 32);
        if (lg == 0) { atomicAdd(&sSQ[col], s); atomicAdd(&sSQ[64 + col], q); }
    }
    __syncthreads();
    short* sX = &sA[0][0];                                // overlay [128][64]
    #pragma unroll
    for (int n = 0; n < 4; ++n) {
        int col = 16 * n + lr;
        float b = sBe[col];
        #pragma unroll
        for (int m = 0; m < 2; ++m)
            #pragma unroll
            for (int r = 0; r < 4; ++r) {
                int row = 32 * w + 16 * m + 4 * lg + r;
                sX[row * 64 + col] = f2bf(acc[m][n][r] + b);
            }
    }
    __syncthreads();
    #pragma unroll
    for (int i = tx; i < 1024; i += 256)
        ((s16x8*)(xbuf + e0 * 64))[i] = ((const s16x8*)sX)[i];
    if (tx < 64) atomicAdd(&st[tx], sSQ[tx]);
    else if (tx < 128) atomicAdd(&st[64 + (tx - 64)], sSQ[tx]);
}

// ------------- Phase 2: y = h_combine @ [W_m|W_s] + bias; stats; store -------
// Stages: nfb gathers are pure bf16 copies; hm = silu(bn_e(x)) computed inline
// from raw xbuf during staging (few hundred VALU/thread, hidden under loads).
// Stores y rows permuted to dst-sorted slot[e] for the atomic-free gather.
__global__ __launch_bounds__(256, 3) void k_y_stats(
    const short* __restrict__ nfb, const int* __restrict__ src,
    const int* __restrict__ dst, const short* __restrict__ xbuf,
    const short* __restrict__ BT, const float* __restrict__ biasY,
    const int* __restrict__ slot, float* __restrict__ st,
    short* __restrict__ ybuf)
{
    __shared__ s16x8 sAv[128 * 24];                      // [128][192] shorts
    short* sA = (short*)sAv;
    __shared__ float sSQ[256];
    __shared__ float sAeCe[128];
    __shared__ float sBias[128];
    __shared__ int   sSlot[128];

    const int tx = threadIdx.x;
    const long e0 = (long)blockIdx.x * 128;

    sSQ[tx] = 0.f;
    if (tx < 128) {
        sAeCe[tx] = st[512 + tx];
        sBias[tx] = biasY[tx];
        sSlot[tx] = slot[e0 + tx];
    }

    const int e = tx >> 1, half = tx & 1;
    {                                                    // stage node rows (copies)
        int sn = src[e0 + e], dn = dst[e0 + e];
        const short* ps = nfb + (size_t)sn * 64 + 32 * half;
        const short* pd = nfb + (size_t)dn * 64 + 32 * half;
        #pragma unroll
        for (int c = 0; c < 32; c += 8) {
            *(s16x8*)&sA[swz(e, 32 * half + c)]      = *(const s16x8*)(ps + c);
            *(s16x8*)&sA[swz(e, 64 + 32 * half + c)] = *(const s16x8*)(pd + c);
        }
    }
    __syncthreads();                                     // sAeCe visible
    {                                                    // stage hm = silu(bn_e(x))
        const short* px = xbuf + (size_t)(e0 + e) * 64 + 32 * half;
        #pragma unroll
        for (int c = 0; c < 32; c += 8) {
            s16x8 xv = *(const s16x8*)(px + c);
            s16x8 hv;
            #pragma unroll
            for (int t = 0; t < 8; ++t) {
                int j = 32 * half + c + t;
                float x = bf2f(xv[t]);
                hv[t] = f2bf(silu_f(fmaf(x, sAeCe[j], sAeCe[64 + j])));
            }
            *(s16x8*)&sA[swz(e, 128 + 32 * half + c)] = hv;
        }
    }
    __syncthreads();

    const int w = tx >> 6, lane = tx & 63, lr = lane & 15, lg = lane >> 4;
    const int wr = w >> 1, wc = w & 1;
    f32x4 acc[4][4];
    for (int m = 0; m < 4; ++m) for (int n = 0; n < 4; ++n)
        for (int q = 0; q < 4; ++q) acc[m][n][q] = 0.f;

    const s16x8* Bg = (const s16x8*)BT;                  // [128 rows][24 frags]
    const int brow = (64 * wc + lr) * 24 + lg;

    #pragma unroll
    for (int ks = 0; ks < 6; ++ks) {
        s16x8 a[4], b[4];
        #pragma unroll
        for (int m = 0; m < 4; ++m)
            a[m] = *(const s16x8*)&sA[swz(64 * wr + 16 * m + lr, ks * 32 + 8 * lg)];
        #pragma unroll
        for (int n = 0; n < 4; ++n)
            b[n] = Bg[brow + 384 * n + 4 * ks];
        #pragma unroll
        for (int m = 0; m < 4; ++m)
            #pragma unroll
            for (int n = 0; n < 4; ++n)
                acc[m][n] = __builtin_amdgcn_mfma_f32_16x16x32_bf16(a[m], b[n], acc[m][n], 0, 0, 0);
    }

    __syncthreads();                                     // all sA frag reads done
    #pragma unroll
    for (int n = 0; n < 4; ++n) {                        // bias + stats + y->LDS
        int col = 64 * wc + 16 * n + lr;
        float b = sBias[col];
        float s = 0.f, q = 0.f;
        #pragma unroll
        for (int m = 0; m < 4; ++m)
            #pragma unroll
            for (int r = 0; r < 4; ++r) {
                float y = acc[m][n][r] + b;
                s += y; q += y * y;
                int row = 64 * wr + 16 * m + 4 * lg + r;
                sA[row * 192 + (col ^ ((row & 7) << 3))] = f2bf(y);
            }
        s += __shfl_xor(s, 16); s += __shfl_xor(s, 32);
        q += __shfl_xor(q, 16); q += __shfl_xor(q, 32);
        if (lg == 0) { atomicAdd(&sSQ[col], s); atomicAdd(&sSQ[128 + col], q); }
    }
    __syncthreads();
    #pragma unroll
    for (int i = tx; i < 2048; i += 256) {               // permuted row store
        int row = i >> 4, frag = i & 15;
        s16x8 v = *(const s16x8*)&sA[swz(row, frag * 8)];
        *(s16x8*)(ybuf + (size_t)sSlot[row] * 128 + frag * 8) = v;
    }
    if (tx < 128) atomicAdd(&st[128 + tx], sSQ[tx]);
    else atomicAdd(&st[256 + (tx - 128)], sSQ[tx]);
}

// ------------- Phase 3: atomic-free gather: one wave per node ----------------
__global__ __launch_bounds__(256) void k_gather(
    const short* __restrict__ ybuf, const int* __restrict__ startF,
    const float* __restrict__ st, float* __restrict__ agg)
{
    __shared__ float sA_[128], sC_[128];
    const int tx = threadIdx.x;
    if (tx < 128) { sA_[tx] = st[640 + tx]; sC_[tx] = st[768 + tx]; }
    __syncthreads();
    const int w = tx >> 6, j = tx & 63;
    const int n = blockIdx.x * 4 + w;
    const int s = startF[n], e = startF[n + 1];
    const float am = sA_[j], cm = sC_[j], as2 = sA_[64 + j], cs2 = sC_[64 + j];
    const short* base = ybuf + (size_t)s * 128;
    const int deg = e - s;
    float acc0 = 0.f, acc1 = 0.f;
    int i = 0;
    for (; i + 2 <= deg; i += 2) {                       // 2-deep for load ILP
        float ym0 = bf2f(base[(size_t)i * 128 + j]);
        float ys0 = bf2f(base[(size_t)i * 128 + 64 + j]);
        float ym1 = bf2f(base[(size_t)(i + 1) * 128 + j]);
        float ys1 = bf2f(base[(size_t)(i + 1) * 128 + 64 + j]);
        acc0 += silu_f(fmaf(ym0, am, cm)) * softplus_f(fmaf(ys0, as2, cs2));
        acc1 += silu_f(fmaf(ym1, am, cm)) * softplus_f(fmaf(ys1, as2, cs2));
    }
    if (i < deg) {
        float ym = bf2f(base[(size_t)i * 128 + j]);
        float ys = bf2f(base[(size_t)i * 128 + 64 + j]);
        acc0 += silu_f(fmaf(ym, am, cm)) * softplus_f(fmaf(ys, as2, cs2));
    }
    agg[(size_t)n * 64 + j] = acc0 + acc1;
}

// ------------- Phase 4: agg column stats -------------------------------------
__global__ __launch_bounds__(256) void k_aggstats(const float* __restrict__ agg,
                                                  float* __restrict__ st)
{
    __shared__ float red[2][4][64];
    float ls = 0.f, lq = 0.f;
    const long total = (long)NN * 64;
    for (long t = (long)blockIdx.x * 256 + threadIdx.x; t < total;
         t += (long)gridDim.x * 256) {
        float a = agg[t];
        ls += a; lq += a * a;
    }
    int j = threadIdx.x & 63, g = threadIdx.x >> 6;
    red[0][g][j] = ls; red[1][g][j] = lq;
    __syncthreads();
    if (threadIdx.x < 64) {
        float s = red[0][0][j] + red[0][1][j] + red[0][2][j] + red[0][3][j];
        atomicAdd(&st[384 + j], s);
    } else if (threadIdx.x < 128) {
        int jj = threadIdx.x - 64;
        float q = red[1][0][jj] + red[1][1][jj] + red[1][2][jj] + red[1][3][jj];
        atomicAdd(&st[448 + jj], q);
    }
}

// ------------- Phase 5: out = softplus(bn_n(agg) + nf), in place -------------
__global__ __launch_bounds__(256) void k_out(float* __restrict__ outagg,
                                             const float* __restrict__ nf,
                                             const float* __restrict__ st)
{
    long t = (long)blockIdx.x * 256 + threadIdx.x;
    int j = (int)(t & 63);
    float a = outagg[t];
    outagg[t] = softplus_f(fmaf(a, st[896 + j], st[960 + j]) + nf[t]);
}

extern "C" void kernel_launch(void* const* d_in, const int* in_sizes, int n_in,
                              void* d_out, int out_size, void* d_ws, size_t ws_size,
                              hipStream_t stream)
{
    (void)in_sizes; (void)n_in; (void)out_size; (void)ws_size;
    const float* nf  = (const float*)d_in[0];
    const float* ef  = (const float*)d_in[1];
    const int*   src = (const int*)d_in[2];
    const int*   dst = (const int*)d_in[3];
    const float* We  = (const float*)d_in[4];
    const float* be_ = (const float*)d_in[5];
    const float* ge  = (const float*)d_in[6];
    const float* bee = (const float*)d_in[7];
    const float* Wm  = (const float*)d_in[8];
    const float* bm  = (const float*)d_in[9];
    const float* gm  = (const float*)d_in[10];
    const float* bem = (const float*)d_in[11];
    const float* Ws  = (const float*)d_in[12];
    const float* bs  = (const float*)d_in[13];
    const float* gs  = (const float*)d_in[14];
    const float* bes = (const float*)d_in[15];
    const float* gn  = (const float*)d_in[16];
    const float* ben = (const float*)d_in[17];

    // ws (proven-size layout)
    float* st    = (float*)d_ws;
    short* xbuf  = (short*)((char*)d_ws + 4096);
    int*   startF= (int*)((char*)d_ws + 4096);            // overlays dead xbuf
    short* ybuf  = (short*)((char*)d_ws + 4096 + 102400000);

    // d_out scratch (dead before k_gather)
    char* ob = (char*)d_out;
    short* BT        = (short*)ob;
    short* BTe       = (short*)(ob + 49152);
    float* biasY     = (float*)(ob + 57344);
    int*   cnt       = (int*)(ob + 57856);
    int*   cur       = (int*)(ob + 257856);
    int*   slot      = (int*)(ob + 457856);
    int*   start_tmp = (int*)(ob + 3657856);
    short* nfb       = (short*)(ob + 3857920);
    float* agg       = (float*)d_out;

    hipMemsetAsync(st, 0, 4096, stream);
    hipMemsetAsync(cnt, 0, 200000, stream);

    k_prep<<<113, 256, 0, stream>>>(Wm, Ws, We, bm, bs, BT, BTe, biasY);
    k_nfb<<<1563, 256, 0, stream>>>(nf, nfb);
    k_hist<<<3125, 256, 0, stream>>>(dst, cnt);
    k_scan<<<1, 256, 0, stream>>>(cnt, start_tmp, cur);
    k_slot<<<3125, 256, 0, stream>>>(dst, cur, slot);

    k_xe_m<<<NE / 128, 256, 0, stream>>>(ef, BTe, be_, st, xbuf);
    k_fin<<<1, 64, 0, stream>>>(st + 0, st + 64, ge, bee, 1.0f / NE, st + 512, st + 576);

    k_y_stats<<<NE / 128, 256, 0, stream>>>(nfb, src, dst, xbuf, BT, biasY, slot, st, ybuf);
    k_finY<<<1, 128, 0, stream>>>(st, gm, bem, gs, bes, st + 640, st + 768);

    k_copy<<<196, 256, 0, stream>>>(start_tmp, startF);   // xbuf now dead
    k_gather<<<NN / 4, 256, 0, stream>>>(ybuf, startF, st, agg);

    k_aggstats<<<1024, 256, 0, stream>>>(agg, st);
    k_fin<<<1, 64, 0, stream>>>(st + 384, st + 448, gn, ben, 1.0f / NN, st + 896, st + 960);

    k_out<<<NN * 64 / 256, 256, 0, stream>>>(agg, nf, st);
}

// Round 6
// 397.225 us; speedup vs baseline: 2.1241x; 1.5238x over previous
//
#include <hip/hip_runtime.h>

#define NN 50000
#define NE 800000
#define EPS 1e-5f

typedef __attribute__((ext_vector_type(8))) short s16x8;
typedef __attribute__((ext_vector_type(4))) short s16x4;
typedef __attribute__((ext_vector_type(4))) float f32x4;

// ---------------------------------------------------------------------------
// ws layout (round-1-proven >= 307,204,096 bytes):
//   0        : st, 1024 floats (4 KB) — only A/C coefficient slots used now
//   4096     : xbuf bf16 [E][64] (102,400,000 B); holds RAW x = ef@We+be.
//              After k_y_stats this region is dead; startF (int[NN+1]) at
//              +4096 and pSQn (32x128 f32) at +266240 overlay it.
//   102404096: ybuf bf16 [E][128], rows permuted to dst-sorted slot order.
// st float offsets: 512 A_e[64], 576 C_e[64], 640 A_y[128], 768 C_y[128],
//                   896 A_n[64], 960 C_n[64]
// d_out (12.8 MB) doubles as scratch until k_gather writes agg:
//   BT @0 (49152), BTe @49152 (8192), biasY @57344 (512), cnt @57856 (200000),
//   cur @257856 (200000), slot @457856 (3200000), start_tmp @3657856 (200004),
//   nfb @3857920 (6400000), pSQe @10257920 (16384), pSQy @10274304 (32768)
//   -- all dead before k_gather runs.
// ---------------------------------------------------------------------------

__device__ __forceinline__ short f2bf(float f) {
    unsigned u = __builtin_bit_cast(unsigned, f);
    unsigned r = (u + 0x7FFFu + ((u >> 16) & 1u)) >> 16;
    return (short)r;
}
__device__ __forceinline__ float bf2f(short s) {
    unsigned u = ((unsigned)(unsigned short)s) << 16;
    return __builtin_bit_cast(float, u);
}
// cheap transcendentals: v_exp/v_log/v_rcp based (tolerance is ~2%)
__device__ __forceinline__ float silu_f(float x) {
    return x * __builtin_amdgcn_rcpf(1.0f + __expf(-x));
}
__device__ __forceinline__ float softplus_f(float x) {
    float t = __expf(-fabsf(x));
    return fmaxf(x, 0.0f) + __logf(1.0f + t);
}
// XOR swizzle for row-major [128][192]-short LDS tile (16 B-slot granularity).
__device__ __forceinline__ int swz(int row, int col) {
    return row * 192 + (col ^ ((row & 7) << 3));
}

// ------------- prep: transpose weights to bf16, combined bias ---------------
__global__ void k_prep(const float* __restrict__ Wm, const float* __restrict__ Ws,
                       const float* __restrict__ We, const float* __restrict__ bm,
                       const float* __restrict__ bs, short* __restrict__ BT,
                       short* __restrict__ BTe, float* __restrict__ biasY)
{
    int i = blockIdx.x * 256 + threadIdx.x;
    if (i < 24576) {
        int n = i / 192, k = i % 192;
        float w = (n < 64) ? Wm[k * 64 + n] : Ws[k * 64 + (n - 64)];
        BT[n * 192 + k] = f2bf(w);
    } else if (i < 28672) {
        int j = i - 24576;
        int n = j >> 6, k = j & 63;
        BTe[n * 64 + k] = f2bf(We[k * 64 + n]);
    } else if (i < 28800) {
        int j = i - 28672;
        biasY[j] = (j < 64) ? bm[j] : bs[j - 64];
    }
}

// ------------- node feats -> bf16 -------------------------------------------
__global__ void k_nfb(const float* __restrict__ nf, short* __restrict__ nfb)
{
    long i = (long)blockIdx.x * 256 + threadIdx.x;      // s16x8 index
    if (i >= (long)NN * 64 / 8) return;
    float4 a = ((const float4*)nf)[i * 2];
    float4 b = ((const float4*)nf)[i * 2 + 1];
    s16x8 o;
    o[0] = f2bf(a.x); o[1] = f2bf(a.y); o[2] = f2bf(a.z); o[3] = f2bf(a.w);
    o[4] = f2bf(b.x); o[5] = f2bf(b.y); o[6] = f2bf(b.z); o[7] = f2bf(b.w);
    ((s16x8*)nfb)[i] = o;
}

// ------------- CSR build -----------------------------------------------------
__global__ void k_hist(const int* __restrict__ dst, int* __restrict__ cnt)
{
    int e = blockIdx.x * 256 + threadIdx.x;
    if (e < NE) atomicAdd(&cnt[dst[e]], 1);
}

__global__ void k_scan(const int* __restrict__ cnt, int* __restrict__ start_tmp,
                       int* __restrict__ cur)
{
    __shared__ int ps[256];
    const int t = threadIdx.x;
    const int CH = 196;                                  // 256*196 = 50176 >= NN
    int base = t * CH;
    int sum = 0;
    for (int i = 0; i < CH; i += 4) {
        int idx = base + i;
        if (idx < NN) { int4 v = *(const int4*)&cnt[idx]; sum += v.x + v.y + v.z + v.w; }
    }
    ps[t] = sum;
    __syncthreads();
    for (int off = 1; off < 256; off <<= 1) {            // inclusive scan
        int v = (t >= off) ? ps[t - off] : 0;
        __syncthreads();
        ps[t] += v;
        __syncthreads();
    }
    int run = (t == 0) ? 0 : ps[t - 1];                  // exclusive prefix
    for (int i = 0; i < CH; i += 4) {
        int idx = base + i;
        if (idx < NN) {
            int4 v = *(const int4*)&cnt[idx];
            int4 o; o.x = run; o.y = run + v.x; o.z = o.y + v.y; o.w = o.z + v.z;
            *(int4*)&start_tmp[idx] = o;
            *(int4*)&cur[idx] = o;
            run = o.w + v.w;
        }
    }
    if (t == 255) start_tmp[NN] = run;                   // == NE
}

__global__ void k_slot(const int* __restrict__ dst, int* __restrict__ cur,
                       int* __restrict__ slot)
{
    int e = blockIdx.x * 256 + threadIdx.x;
    if (e < NE) slot[e] = atomicAdd(&cur[dst[e]], 1);
}

__global__ void k_copy(const int* __restrict__ a, int* __restrict__ b)
{
    int i = blockIdx.x * 256 + threadIdx.x;
    if (i <= NN) b[i] = a[i];
}

// ------------- BN finalize from 32 replicated partial buckets ----------------
// partials layout: [32 reps][S[ncols] | Q[ncols]]
__global__ void k_fin_r(const float* __restrict__ P, const float* __restrict__ g,
                        const float* __restrict__ b, float inv_cnt, int ncols,
                        float* __restrict__ A, float* __restrict__ C)
{
    int j = threadIdx.x;
    if (j >= ncols) return;
    float S = 0.f, Q = 0.f;
    for (int r = 0; r < 32; ++r) {
        S += P[r * 2 * ncols + j];
        Q += P[r * 2 * ncols + ncols + j];
    }
    float m = S * inv_cnt;
    float v = Q * inv_cnt - m * m;
    float a = g[j] * rsqrtf(v + EPS);
    A[j] = a;
    C[j] = b[j] - m * a;
}

// merged finalize for both y-BNs (j 0..127: m-half then s-half)
__global__ void k_finY_r(const float* __restrict__ P,
                         const float* __restrict__ gm, const float* __restrict__ bem,
                         const float* __restrict__ gs, const float* __restrict__ bes,
                         float* __restrict__ A, float* __restrict__ C)
{
    int j = threadIdx.x;                                 // 128
    float S = 0.f, Q = 0.f;
    for (int r = 0; r < 32; ++r) {
        S += P[r * 256 + j];
        Q += P[r * 256 + 128 + j];
    }
    float g = (j < 64) ? gm[j] : gs[j - 64];
    float b = (j < 64) ? bem[j] : bes[j - 64];
    float m = S * (1.0f / NE);
    float v = Q * (1.0f / NE) - m * m;
    float a = g * rsqrtf(v + EPS);
    A[j] = a;
    C[j] = b - m * a;
}

// ------------- Phase 1: x = ef @ W_e + b_e (MFMA bf16); stats; store xbuf ----
// 512 threads, 8 waves (4 row-blocks x 2 col-blocks of 32x32) -> 32 waves/CU.
__global__ __launch_bounds__(512, 4) void k_xe_m(
    const float* __restrict__ ef, const short* __restrict__ BTe,
    const float* __restrict__ be_, float* __restrict__ pSQe,
    short* __restrict__ xbuf)
{
    __shared__ short sA[128][72];
    __shared__ short sB[64][72];
    __shared__ float sSQ[128];
    __shared__ float sBe[64];
    const int tx = threadIdx.x;
    const long e0 = (long)blockIdx.x * 128;

    if (tx < 128) sSQ[tx] = 0.f;
    if (tx < 64) sBe[tx] = be_[tx];
    {                                                    // stage W_e^T: 512 frags
        int n = tx >> 3, c = (tx & 7) * 8;
        *(s16x8*)&sB[n][c] = ((const s16x8*)BTe)[tx];
    }
    {                                                    // stage A (fp32->bf16)
        const int e = tx >> 2, q4 = tx & 3;
        const float* p = ef + (e0 + e) * 64 + q4 * 16;
        #pragma unroll
        for (int c = 0; c < 16; c += 4) {
            float4 v = *(const float4*)(p + c);
            s16x4 w; w.x = f2bf(v.x); w.y = f2bf(v.y); w.z = f2bf(v.z); w.w = f2bf(v.w);
            *(s16x4*)&sA[e][q4 * 16 + c] = w;
        }
    }
    __syncthreads();

    const int w = tx >> 6, lane = tx & 63, lr = lane & 15, lg = lane >> 4;
    const int wr = w >> 1, wc = w & 1;                   // 4 x 2 wave grid
    f32x4 acc[2][2];
    for (int m = 0; m < 2; ++m) for (int n = 0; n < 2; ++n)
        for (int q = 0; q < 4; ++q) acc[m][n][q] = 0.f;

    #pragma unroll
    for (int ks = 0; ks < 2; ++ks) {
        s16x8 a[2], b[2];
        #pragma unroll
        for (int m = 0; m < 2; ++m) a[m] = *(const s16x8*)&sA[32 * wr + 16 * m + lr][ks * 32 + 8 * lg];
        #pragma unroll
        for (int n = 0; n < 2; ++n) b[n] = *(const s16x8*)&sB[32 * wc + 16 * n + lr][ks * 32 + 8 * lg];
        #pragma unroll
        for (int m = 0; m < 2; ++m)
            #pragma unroll
            for (int n = 0; n < 2; ++n)
                acc[m][n] = __builtin_amdgcn_mfma_f32_16x16x32_bf16(a[m], b[n], acc[m][n], 0, 0, 0);
    }

    #pragma unroll
    for (int n = 0; n < 2; ++n) {                        // bias + stats
        int col = 32 * wc + 16 * n + lr;
        float b = sBe[col];
        float s = 0.f, q = 0.f;
        #pragma unroll
        for (int m = 0; m < 2; ++m)
            #pragma unroll
            for (int r = 0; r < 4; ++r) { float y = acc[m][n][r] + b; s += y; q += y * y; }
        s += __shfl_xor(s, 16); s += __shfl_xor(s, 32);
        q += __shfl_xor(q, 16); q += __shfl_xor(q, 32);
        if (lg == 0) { atomicAdd(&sSQ[col], s); atomicAdd(&sSQ[64 + col], q); }
    }
    __syncthreads();
    short* sX = &sA[0][0];                                // overlay [128][64]
    #pragma unroll
    for (int n = 0; n < 2; ++n) {
        int col = 32 * wc + 16 * n + lr;
        float b = sBe[col];
        #pragma unroll
        for (int m = 0; m < 2; ++m)
            #pragma unroll
            for (int r = 0; r < 4; ++r) {
                int row = 32 * wr + 16 * m + 4 * lg + r;
                sX[row * 64 + col] = f2bf(acc[m][n][r] + b);
            }
    }
    __syncthreads();
    #pragma unroll
    for (int i = tx; i < 1024; i += 512)
        ((s16x8*)(xbuf + e0 * 64))[i] = ((const s16x8*)sX)[i];
    if (tx < 128) atomicAdd(&pSQe[(blockIdx.x & 31) * 128 + tx], sSQ[tx]);
}

// ------------- Phase 2: y = h_combine @ [W_m|W_s] + bias; stats; store -------
// 512 threads, 8 waves (2 row-blocks x 4 col-blocks; each wave 64x32 out).
// Stores y rows permuted to dst-sorted slot[e] for the atomic-free gather.
__global__ __launch_bounds__(512, 3) void k_y_stats(
    const short* __restrict__ nfb, const int* __restrict__ src,
    const int* __restrict__ dst, const short* __restrict__ xbuf,
    const short* __restrict__ BT, const float* __restrict__ biasY,
    const int* __restrict__ slot, const float* __restrict__ st,
    float* __restrict__ pSQy, short* __restrict__ ybuf)
{
    __shared__ s16x8 sAv[128 * 24];                      // [128][192] shorts
    short* sA = (short*)sAv;
    __shared__ float sSQ[256];
    __shared__ float sAeCe[128];
    __shared__ float sBias[128];
    __shared__ int   sSlot[128];

    const int tx = threadIdx.x;
    const long e0 = (long)blockIdx.x * 128;

    if (tx < 256) sSQ[tx] = 0.f;
    if (tx < 128) {
        sAeCe[tx] = st[512 + tx];
        sBias[tx] = biasY[tx];
        sSlot[tx] = slot[e0 + tx];
    }

    const int e = tx >> 2, q4 = tx & 3;                  // 4 threads/edge
    {                                                    // stage node rows (copies)
        int sn = src[e0 + e], dn = dst[e0 + e];
        const short* ps = nfb + (size_t)sn * 64 + q4 * 16;
        const short* pd = nfb + (size_t)dn * 64 + q4 * 16;
        #pragma unroll
        for (int c = 0; c < 16; c += 8) {
            *(s16x8*)&sA[swz(e, q4 * 16 + c)]      = *(const s16x8*)(ps + c);
            *(s16x8*)&sA[swz(e, 64 + q4 * 16 + c)] = *(const s16x8*)(pd + c);
        }
    }
    __syncthreads();                                     // sAeCe visible
    {                                                    // stage hm = silu(bn_e(x))
        const short* px = xbuf + (size_t)(e0 + e) * 64 + q4 * 16;
        #pragma unroll
        for (int c = 0; c < 16; c += 8) {
            s16x8 xv = *(const s16x8*)(px + c);
            s16x8 hv;
            #pragma unroll
            for (int t = 0; t < 8; ++t) {
                int j = q4 * 16 + c + t;
                float x = bf2f(xv[t]);
                hv[t] = f2bf(silu_f(fmaf(x, sAeCe[j], sAeCe[64 + j])));
            }
            *(s16x8*)&sA[swz(e, 128 + q4 * 16 + c)] = hv;
        }
    }
    __syncthreads();

    const int w = tx >> 6, lane = tx & 63, lr = lane & 15, lg = lane >> 4;
    const int wr = w >> 2, wc = w & 3;                   // 2 x 4 wave grid
    f32x4 acc[4][2];
    for (int m = 0; m < 4; ++m) for (int n = 0; n < 2; ++n)
        for (int q = 0; q < 4; ++q) acc[m][n][q] = 0.f;

    const s16x8* Bg = (const s16x8*)BT;                  // [128 rows][24 frags]
    const int brow = (32 * wc + lr) * 24 + lg;

    #pragma unroll
    for (int ks = 0; ks < 6; ++ks) {
        s16x8 a[4], b[2];
        #pragma unroll
        for (int m = 0; m < 4; ++m)
            a[m] = *(const s16x8*)&sA[swz(64 * wr + 16 * m + lr, ks * 32 + 8 * lg)];
        #pragma unroll
        for (int n = 0; n < 2; ++n)
            b[n] = Bg[brow + 384 * n + 4 * ks];
        #pragma unroll
        for (int m = 0; m < 4; ++m)
            #pragma unroll
            for (int n = 0; n < 2; ++n)
                acc[m][n] = __builtin_amdgcn_mfma_f32_16x16x32_bf16(a[m], b[n], acc[m][n], 0, 0, 0);
    }

    __syncthreads();                                     // all sA frag reads done
    #pragma unroll
    for (int n = 0; n < 2; ++n) {                        // bias + stats + y->LDS
        int col = 32 * wc + 16 * n + lr;
        float b = sBias[col];
        float s = 0.f, q = 0.f;
        #pragma unroll
        for (int m = 0; m < 4; ++m)
            #pragma unroll
            for (int r = 0; r < 4; ++r) {
                float y = acc[m][n][r] + b;
                s += y; q += y * y;
                int row = 64 * wr + 16 * m + 4 * lg + r;
                sA[row * 192 + (col ^ ((row & 7) << 3))] = f2bf(y);
            }
        s += __shfl_xor(s, 16); s += __shfl_xor(s, 32);
        q += __shfl_xor(q, 16); q += __shfl_xor(q, 32);
        if (lg == 0) { atomicAdd(&sSQ[col], s); atomicAdd(&sSQ[128 + col], q); }
    }
    __syncthreads();
    #pragma unroll
    for (int i = tx; i < 2048; i += 512) {               // permuted row store
        int row = i >> 4, frag = i & 15;
        s16x8 v = *(const s16x8*)&sA[swz(row, frag * 8)];
        *(s16x8*)(ybuf + (size_t)sSlot[row] * 128 + frag * 8) = v;
    }
    if (tx < 256) atomicAdd(&pSQy[(blockIdx.x & 31) * 256 + tx], sSQ[tx]);
}

// ------------- Phase 3: atomic-free gather + fused node BN stats -------------
__global__ __launch_bounds__(256) void k_gather(
    const short* __restrict__ ybuf, const int* __restrict__ startF,
    const float* __restrict__ st, float* __restrict__ pSQn,
    float* __restrict__ agg)
{
    __shared__ float sA_[128], sC_[128];
    __shared__ float sS[4][64], sQv[4][64];
    const int tx = threadIdx.x;
    if (tx < 128) { sA_[tx] = st[640 + tx]; sC_[tx] = st[768 + tx]; }
    __syncthreads();
    const int w = tx >> 6, j = tx & 63;
    const int n = blockIdx.x * 4 + w;
    const int s = startF[n], e = startF[n + 1];
    const float am = sA_[j], cm = sC_[j], as2 = sA_[64 + j], cs2 = sC_[64 + j];
    const short* base = ybuf + (size_t)s * 128;
    const int deg = e - s;
    float acc0 = 0.f, acc1 = 0.f;
    int i = 0;
    for (; i + 2 <= deg; i += 2) {                       // 2-deep for load ILP
        float ym0 = bf2f(base[(size_t)i * 128 + j]);
        float ys0 = bf2f(base[(size_t)i * 128 + 64 + j]);
        float ym1 = bf2f(base[(size_t)(i + 1) * 128 + j]);
        float ys1 = bf2f(base[(size_t)(i + 1) * 128 + 64 + j]);
        acc0 += silu_f(fmaf(ym0, am, cm)) * softplus_f(fmaf(ys0, as2, cs2));
        acc1 += silu_f(fmaf(ym1, am, cm)) * softplus_f(fmaf(ys1, as2, cs2));
    }
    if (i < deg) {
        float ym = bf2f(base[(size_t)i * 128 + j]);
        float ys = bf2f(base[(size_t)i * 128 + 64 + j]);
        acc0 += silu_f(fmaf(ym, am, cm)) * softplus_f(fmaf(ys, as2, cs2));
    }
    float a = acc0 + acc1;
    agg[(size_t)n * 64 + j] = a;
    sS[w][j] = a; sQv[w][j] = a * a;                     // fused node-BN stats
    __syncthreads();
    if (tx < 64) {
        float s2 = sS[0][tx] + sS[1][tx] + sS[2][tx] + sS[3][tx];
        atomicAdd(&pSQn[(blockIdx.x & 31) * 128 + tx], s2);
    } else if (tx < 128) {
        int jj = tx - 64;
        float q2 = sQv[0][jj] + sQv[1][jj] + sQv[2][jj] + sQv[3][jj];
        atomicAdd(&pSQn[(blockIdx.x & 31) * 128 + 64 + jj], q2);
    }
}

// ------------- Phase 5: out = softplus(bn_n(agg) + nf), in place -------------
__global__ __launch_bounds__(256) void k_out(float* __restrict__ outagg,
                                             const float* __restrict__ nf,
                                             const float* __restrict__ st)
{
    long t = (long)blockIdx.x * 256 + threadIdx.x;
    int j = (int)(t & 63);
    float a = outagg[t];
    outagg[t] = softplus_f(fmaf(a, st[896 + j], st[960 + j]) + nf[t]);
}

extern "C" void kernel_launch(void* const* d_in, const int* in_sizes, int n_in,
                              void* d_out, int out_size, void* d_ws, size_t ws_size,
                              hipStream_t stream)
{
    (void)in_sizes; (void)n_in; (void)out_size; (void)ws_size;
    const float* nf  = (const float*)d_in[0];
    const float* ef  = (const float*)d_in[1];
    const int*   src = (const int*)d_in[2];
    const int*   dst = (const int*)d_in[3];
    const float* We  = (const float*)d_in[4];
    const float* be_ = (const float*)d_in[5];
    const float* ge  = (const float*)d_in[6];
    const float* bee = (const float*)d_in[7];
    const float* Wm  = (const float*)d_in[8];
    const float* bm  = (const float*)d_in[9];
    const float* gm  = (const float*)d_in[10];
    const float* bem = (const float*)d_in[11];
    const float* Ws  = (const float*)d_in[12];
    const float* bs  = (const float*)d_in[13];
    const float* gs  = (const float*)d_in[14];
    const float* bes = (const float*)d_in[15];
    const float* gn  = (const float*)d_in[16];
    const float* ben = (const float*)d_in[17];

    // ws layout
    float* st    = (float*)d_ws;
    short* xbuf  = (short*)((char*)d_ws + 4096);
    int*   startF= (int*)((char*)d_ws + 4096);            // overlays dead xbuf
    float* pSQn  = (float*)((char*)d_ws + 266240);        // overlays dead xbuf
    short* ybuf  = (short*)((char*)d_ws + 4096 + 102400000);

    // d_out scratch (dead before k_gather)
    char* ob = (char*)d_out;
    short* BT        = (short*)ob;
    short* BTe       = (short*)(ob + 49152);
    float* biasY     = (float*)(ob + 57344);
    int*   cnt       = (int*)(ob + 57856);
    int*   cur       = (int*)(ob + 257856);
    int*   slot      = (int*)(ob + 457856);
    int*   start_tmp = (int*)(ob + 3657856);
    short* nfb       = (short*)(ob + 3857920);
    float* pSQe      = (float*)(ob + 10257920);
    float* pSQy      = (float*)(ob + 10274304);
    float* agg       = (float*)d_out;

    hipMemsetAsync(cnt, 0, 200000, stream);
    hipMemsetAsync(pSQe, 0, 16384 + 32768, stream);       // pSQe + pSQy

    k_prep<<<113, 256, 0, stream>>>(Wm, Ws, We, bm, bs, BT, BTe, biasY);
    k_nfb<<<1563, 256, 0, stream>>>(nf, nfb);
    k_hist<<<3125, 256, 0, stream>>>(dst, cnt);
    k_scan<<<1, 256, 0, stream>>>(cnt, start_tmp, cur);
    k_slot<<<3125, 256, 0, stream>>>(dst, cur, slot);

    k_xe_m<<<NE / 128, 512, 0, stream>>>(ef, BTe, be_, pSQe, xbuf);
    k_fin_r<<<1, 64, 0, stream>>>(pSQe, ge, bee, 1.0f / NE, 64, st + 512, st + 576);

    k_y_stats<<<NE / 128, 512, 0, stream>>>(nfb, src, dst, xbuf, BT, biasY, slot, st, pSQy, ybuf);
    k_finY_r<<<1, 128, 0, stream>>>(pSQy, gm, bem, gs, bes, st + 640, st + 768);

    k_copy<<<196, 256, 0, stream>>>(start_tmp, startF);   // xbuf now dead
    hipMemsetAsync(pSQn, 0, 16384, stream);
    k_gather<<<NN / 4, 256, 0, stream>>>(ybuf, startF, st, pSQn, agg);
    k_fin_r<<<1, 64, 0, stream>>>(pSQn, gn, ben, 1.0f / NN, 64, st + 896, st + 960);

    k_out<<<NN * 64 / 256, 256, 0, stream>>>(agg, nf, st);
}